// Round 5
// baseline (195.829 us; speedup 1.0000x reference)
//
#include <hip/hip_runtime.h>
#include <hip/hip_bf16.h>
#include <stdint.h>
#include <type_traits>

#define BSAMP 8192
#define NCLS 400
#define DIM 768
#define LOGITS_SIZE (16384LL * 400LL)
#define GEMM_BLOCKS 640     // 128 m-bands(128 rows) x 5 n(80 cols); XCD-remapped in-kernel
#define MASK_BLOCKS 4096    // 4 (sample,box) pairs per block, 1 per wave
#define W_ELEMS (NCLS * DIM)

typedef __attribute__((ext_vector_type(8))) short short8;
typedef __attribute__((ext_vector_type(4))) float floatx4;

// fp32 -> bf16 round-half-up, two at a time: 2 adds + 1 v_perm
__device__ inline unsigned int packbf(float a, float b) {
    unsigned int ua = __float_as_uint(a) + 0x8000u;
    unsigned int ub = __float_as_uint(b) + 0x8000u;
    return __builtin_amdgcn_perm(ub, ua, 0x07060302u);  // [ua.b2,ua.b3,ub.b2,ub.b3]
}

__device__ inline short8 cvt8(float4 lo, float4 hi) {
    union { unsigned int u[4]; short8 s; } r;
    r.u[0] = packbf(lo.x, lo.y);
    r.u[1] = packbf(lo.z, lo.w);
    r.u[2] = packbf(hi.x, hi.y);
    r.u[3] = packbf(hi.z, hi.w);
    return r.s;
}

// W fp32 -> bf16 pre-convert (0.6 MB into d_ws); re-run every launch (ws re-poisoned)
__global__ void cvtW_kernel(const float* __restrict__ W, unsigned short* __restrict__ ws) {
    int i = (blockIdx.x * 256 + threadIdx.x) * 4;
    if (i < W_ELEMS) {
        float4 f = *(const float4*)(W + i);
        uint2 r;
        r.x = packbf(f.x, f.y);
        r.y = packbf(f.z, f.w);
        *(uint2*)(ws + i) = r;
    }
}

// 2x2 tap: identical expressions to the reference's inner bilinear (coord chain hoisted)
__device__ inline float tap4(const float* m14, int r0, int c0, float fy, float fx) {
    int r1 = min(r0 + 1, 13);
    int c1 = min(c0 + 1, 13);
    float g00 = m14[r0 * 14 + c0];
    float g01 = m14[r0 * 14 + c1];
    float g10 = m14[r1 * 14 + c0];
    float g11 = m14[r1 * 14 + c1];
    return g00 * (1.f - fy) * (1.f - fx) + g01 * (1.f - fy) * fx +
           g10 * fy * (1.f - fx) + g11 * fy * fx;
}

// ===================== GEMM kernel: 128(M) x 80(N); NO LDS, NO BARRIERS =====================
// R4 post-mortem: barrier-drained LDS staging was the serializer (53 us, VALUBusy 7%).
// B is fetched per-lane from the bf16 workspace (L2-hot: 120 KB XCD slice), A per-lane
// from E. 3-deep A / 2-deep B register pipelines; every wave free-runs its own chain.
template <bool USE_WS>
__global__ __launch_bounds__(256, 3) void gemm_kernel(const float* __restrict__ E,
                                                      const float* __restrict__ W,
                                                      const float* __restrict__ bias,
                                                      const unsigned short* __restrict__ wsW,
                                                      float* __restrict__ out) {
    const int bx = blockIdx.x;
    const int t  = threadIdx.x;
    const int wv = t >> 6, ln = t & 63;

    // XCD remap: 640 = 8 XCDs * 80; 80 = 16 bands * 5 n (bijective). All 5 n-sharers
    // of an A band land on the same XCD, adjacent in dispatch -> A + W L2-resident.
    const int xcd = bx & 7;
    const int j   = bx >> 3;            // 0..79
    const int n0  = (j % 5) * 80;
    const int m0  = (xcd * 16 + j / 5) * 128;
    const int quad = ln >> 4, l16 = ln & 15;

    // A frag source: lane (quad,l16) needs rows (wv*32+l16, +16), k = it*32 + quad*8..+7
    const float* aptr0 = E + (size_t)(m0 + wv * 32 + l16) * DIM + quad * 8;
    const float* aptr1 = aptr0 + (size_t)16 * DIM;

    floatx4 acc[2][5];
#pragma unroll
    for (int g = 0; g < 2; ++g)
#pragma unroll
        for (int ni = 0; ni < 5; ++ni) acc[g][ni] = (floatx4){0.f, 0.f, 0.f, 0.f};

    if constexpr (USE_WS) {
        // B frag source: lane (quad,l16) needs B[col = n0+ni*16+l16][k = it*32+quad*8..+7]
        // = wsW + (n0+ni*16+l16)*DIM + it*32 + quad*8  -> 16 B/lane, same values the old
        // LDS path delivered (bit-identical numerics).
        const unsigned short* bptr = wsW + (size_t)(n0 + l16) * DIM + quad * 8;

        float4 pa[3][4];    // 3-deep A pipeline (48 VGPR)
        short8 pb_[2][5];   // 2-deep B pipeline (40 VGPR)

        auto LDA = [&](int it, int d) {
            pa[d][0] = *(const float4*)(aptr0 + it * 32);
            pa[d][1] = *(const float4*)(aptr0 + it * 32 + 4);
            pa[d][2] = *(const float4*)(aptr1 + it * 32);
            pa[d][3] = *(const float4*)(aptr1 + it * 32 + 4);
        };
        auto LDB = [&](int it, int d) {
#pragma unroll
            for (int ni = 0; ni < 5; ++ni)
                pb_[d][ni] = *(const short8*)(bptr + (size_t)ni * 16 * DIM + it * 32);
        };

        // prologue: fill pipelines
        LDA(0, 0); LDA(1, 1); LDA(2, 2);
        LDB(0, 0); LDB(1, 1);

#pragma unroll
        for (int it = 0; it < 24; ++it) {
            const int ia = it % 3, ib = it & 1;
            // consume old pipeline slots into SSA temps BEFORE re-issuing into them
            short8 b0 = pb_[ib][0], b1 = pb_[ib][1], b2 = pb_[ib][2],
                   b3 = pb_[ib][3], b4 = pb_[ib][4];
            short8 af0 = cvt8(pa[ia][0], pa[ia][1]);
            short8 af1 = cvt8(pa[ia][2], pa[ia][3]);
            if (it < 21) LDA(it + 3, ia);   // static guards (full unroll)
            if (it < 22) LDB(it + 2, ib);
            acc[0][0] = __builtin_amdgcn_mfma_f32_16x16x32_bf16(af0, b0, acc[0][0], 0, 0, 0);
            acc[1][0] = __builtin_amdgcn_mfma_f32_16x16x32_bf16(af1, b0, acc[1][0], 0, 0, 0);
            acc[0][1] = __builtin_amdgcn_mfma_f32_16x16x32_bf16(af0, b1, acc[0][1], 0, 0, 0);
            acc[1][1] = __builtin_amdgcn_mfma_f32_16x16x32_bf16(af1, b1, acc[1][1], 0, 0, 0);
            acc[0][2] = __builtin_amdgcn_mfma_f32_16x16x32_bf16(af0, b2, acc[0][2], 0, 0, 0);
            acc[1][2] = __builtin_amdgcn_mfma_f32_16x16x32_bf16(af1, b2, acc[1][2], 0, 0, 0);
            acc[0][3] = __builtin_amdgcn_mfma_f32_16x16x32_bf16(af0, b3, acc[0][3], 0, 0, 0);
            acc[1][3] = __builtin_amdgcn_mfma_f32_16x16x32_bf16(af1, b3, acc[1][3], 0, 0, 0);
            acc[0][4] = __builtin_amdgcn_mfma_f32_16x16x32_bf16(af0, b4, acc[0][4], 0, 0, 0);
            acc[1][4] = __builtin_amdgcn_mfma_f32_16x16x32_bf16(af1, b4, acc[1][4], 0, 0, 0);
        }
    } else {
        // fallback (no workspace): B per-lane from global fp32
#pragma unroll 4
        for (int it = 0; it < 24; ++it) {
            short8 af0 = cvt8(*(const float4*)(aptr0 + it * 32), *(const float4*)(aptr0 + it * 32 + 4));
            short8 af1 = cvt8(*(const float4*)(aptr1 + it * 32), *(const float4*)(aptr1 + it * 32 + 4));
#pragma unroll
            for (int ni = 0; ni < 5; ++ni) {
                const float* wp = W + (size_t)(n0 + ni * 16 + l16) * DIM + it * 32 + quad * 8;
                short8 bfr = cvt8(*(const float4*)wp, *(const float4*)(wp + 4));
                acc[0][ni] = __builtin_amdgcn_mfma_f32_16x16x32_bf16(af0, bfr, acc[0][ni], 0, 0, 0);
                acc[1][ni] = __builtin_amdgcn_mfma_f32_16x16x32_bf16(af1, bfr, acc[1][ni], 0, 0, 0);
            }
        }
    }

    // epilogue: C/D layout col=lane&15, row=quad*4+reg (HW-verified)
    const int rowBase = m0 + wv * 32 + quad * 4;
#pragma unroll
    for (int ni = 0; ni < 5; ++ni) {
        int col = n0 + ni * 16 + l16;
        float bv = bias[col];
#pragma unroll
        for (int r = 0; r < 4; ++r) {
            out[(size_t)(rowBase + r) * NCLS + col]      = acc[0][ni][r] + bv;
            out[(size_t)(rowBase + 16 + r) * NCLS + col] = acc[1][ni][r] + bv;
        }
    }
}

// ===================== mask kernel: 4 (sample,box) pairs per block, 1 per wave =====================
struct MaskSm { float m14[4][208]; float a7[4][56]; float mv[4][56]; };  // 5120 B

__global__ __launch_bounds__(256, 8) void mask_kernel(const float* __restrict__ attn,
                                                      const int* __restrict__ pos,
                                                      float* __restrict__ out) {
    __shared__ __align__(16) MaskSm sm;

    const int bx = blockIdx.x;
    const int t  = threadIdx.x;
    const int wv = t >> 6, ln = t & 63;

    // pairing: waves (2k, 2k+1) hold (b, o=0) and (b, o=1) of the SAME sample ->
    // the 784-B attn row is fetched from HBM once per block instead of twice globally.
    const int p = bx * 4 + wv;   // 0..16383
    const int b = p >> 1;
    const int o = p & 1;
    float* m14 = sm.m14[wv];

    for (int i = ln; i < 196; i += 64) m14[i] = attn[(size_t)b * 196 + i];

    const int* pb = pos + (size_t)b * 12;
    const float topf  = (float)(pb[o * 4 + 0] - pb[8]);
    const float leftf = (float)(pb[o * 4 + 1] - pb[9]);
    const float oH = (float)pb[o * 4 + 2];
    const float oW = (float)pb[o * 4 + 3];
    const float eH = (float)pb[10];
    const float eW = (float)pb[11];
    __syncthreads();

    const int i7 = ln / 7, j7 = ln - i7 * 7;
    if (ln < 49) {
        // hoisted coordinate chains (identical expressions to reference; computed once)
        int   cI[2][2];  float cF[2][2];  float wxs[2];   // [dx][which X]
        int   rI[2][2];  float rF[2][2];  float wys[2];   // [dy][which Y]
#pragma unroll
        for (int dx = 0; dx < 2; ++dx) {
            int ox = 2 * j7 + dx;
            float tx = fmaxf((ox + 0.5f) * oW / 14.0f - 0.5f, 0.0f);
            float x0 = floorf(tx);
            float x1 = fminf(x0 + 1.0f, oW - 1.0f);
            wxs[dx] = tx - x0;
            float X0 = leftf + x0, X1 = leftf + x1;
            float sx0 = fmaxf((X0 + 0.5f) * 14.0f / eW - 0.5f, 0.0f);
            float c0f = floorf(sx0);
            cI[dx][0] = (int)c0f; cF[dx][0] = sx0 - c0f;
            float sx1 = fmaxf((X1 + 0.5f) * 14.0f / eW - 0.5f, 0.0f);
            float c1f = floorf(sx1);
            cI[dx][1] = (int)c1f; cF[dx][1] = sx1 - c1f;
        }
#pragma unroll
        for (int dy = 0; dy < 2; ++dy) {
            int oy = 2 * i7 + dy;
            float ty = fmaxf((oy + 0.5f) * oH / 14.0f - 0.5f, 0.0f);
            float y0 = floorf(ty);
            float y1 = fminf(y0 + 1.0f, oH - 1.0f);
            wys[dy] = ty - y0;
            float Y0 = topf + y0, Y1 = topf + y1;
            float sy0 = fmaxf((Y0 + 0.5f) * 14.0f / eH - 0.5f, 0.0f);
            float r0f = floorf(sy0);
            rI[dy][0] = (int)r0f; rF[dy][0] = sy0 - r0f;
            float sy1 = fmaxf((Y1 + 0.5f) * 14.0f / eH - 0.5f, 0.0f);
            float r1f = floorf(sy1);
            rI[dy][1] = (int)r1f; rF[dy][1] = sy1 - r1f;
        }

        float s = 0.f;
#pragma unroll
        for (int dy = 0; dy < 2; ++dy) {
            float wy = wys[dy];
#pragma unroll
            for (int dx = 0; dx < 2; ++dx) {
                float wx = wxs[dx];
                float v00 = tap4(m14, rI[dy][0], cI[dx][0], rF[dy][0], cF[dx][0]);
                float v01 = tap4(m14, rI[dy][0], cI[dx][1], rF[dy][0], cF[dx][1]);
                float v10 = tap4(m14, rI[dy][1], cI[dx][0], rF[dy][1], cF[dx][0]);
                float v11 = tap4(m14, rI[dy][1], cI[dx][1], rF[dy][1], cF[dx][1]);
                float cm = v00 * (1.f - wy) * (1.f - wx) + v01 * (1.f - wy) * wx +
                           v10 * wy * (1.f - wx) + v11 * wy * wx;
                s += cm;
            }
        }
        sm.a7[wv][ln] = s * 0.25f;
    }
    __syncthreads();

    if (ln < 49) {  // stable top-25 rank (jax.lax.top_k tie-break to lower index)
        float mine = sm.a7[wv][ln];
        int cnt = 0;
#pragma unroll 7
        for (int s2 = 0; s2 < 49; ++s2) {
            float v = sm.a7[wv][s2];
            cnt += (v > mine) || (v == mine && s2 < ln);
        }
        sm.mv[wv][ln] = (cnt < 25) ? 0.0f : 1.0f;
    }
    __syncthreads();

    float* ob = out + LOGITS_SIZE + (size_t)(o * BSAMP + b) * 196;
    for (int i = ln; i < 196; i += 64) {
        int oy = i / 14, ox = i - oy * 14;
        ob[i] = sm.mv[wv][(oy >> 1) * 7 + (ox >> 1)];
    }
}

extern "C" void kernel_launch(void* const* d_in, const int* in_sizes, int n_in,
                              void* d_out, int out_size, void* d_ws, size_t ws_size,
                              hipStream_t stream) {
    const float* attn = (const float*)d_in[0];
    const int*   pos  = (const int*)d_in[1];
    const float* E    = (const float*)d_in[2];
    const float* W    = (const float*)d_in[3];
    const float* bias = (const float*)d_in[4];
    float* out = (float*)d_out;

    if (ws_size >= (size_t)W_ELEMS * 2) {
        unsigned short* ws = (unsigned short*)d_ws;
        cvtW_kernel<<<300, 256, 0, stream>>>(W, ws);
        gemm_kernel<true><<<GEMM_BLOCKS, 256, 0, stream>>>(E, W, bias, ws, out);
    } else {
        gemm_kernel<false><<<GEMM_BLOCKS, 256, 0, stream>>>(E, W, bias, nullptr, out);
    }
    mask_kernel<<<MASK_BLOCKS, 256, 0, stream>>>(attn, pos, out);
}

// Round 6
// 165.785 us; speedup vs baseline: 1.1812x; 1.1812x over previous
//
#include <hip/hip_runtime.h>
#include <hip/hip_bf16.h>
#include <stdint.h>
#include <type_traits>

#define BSAMP 8192
#define NCLS 400
#define DIM 768
#define LOGITS_SIZE (16384LL * 400LL)
#define GEMM_BLOCKS 1280    // 256 m-bands(64 rows) x 5 n(80 cols); XCD-remapped in-kernel
#define MASK_BLOCKS 4096    // 4 (sample,box) pairs per block, 1 per wave
#define W_ELEMS (NCLS * DIM)

typedef __attribute__((ext_vector_type(8))) short short8;
typedef __attribute__((ext_vector_type(4))) float floatx4;

// fp32 -> bf16 round-half-up, two at a time: 2 adds + 1 v_perm
__device__ inline unsigned int packbf(float a, float b) {
    unsigned int ua = __float_as_uint(a) + 0x8000u;
    unsigned int ub = __float_as_uint(b) + 0x8000u;
    return __builtin_amdgcn_perm(ub, ua, 0x07060302u);  // [ua.b2,ua.b3,ub.b2,ub.b3]
}

__device__ inline short8 cvt8(float4 lo, float4 hi) {
    union { unsigned int u[4]; short8 s; } r;
    r.u[0] = packbf(lo.x, lo.y);
    r.u[1] = packbf(lo.z, lo.w);
    r.u[2] = packbf(hi.x, hi.y);
    r.u[3] = packbf(hi.z, hi.w);
    return r.s;
}

// async global->LDS DMA, 16 B/lane, dest = wave-uniform base + lane*16.
__device__ inline void gload16(const void* g, void* l) {
    __builtin_amdgcn_global_load_lds((const __attribute__((address_space(1))) void*)g,
                                     (__attribute__((address_space(3))) void*)l, 16, 0, 0);
}

// W fp32 -> bf16 pre-convert (0.6 MB into d_ws); re-run every launch (ws re-poisoned)
__global__ void cvtW_kernel(const float* __restrict__ W, unsigned short* __restrict__ ws) {
    int i = (blockIdx.x * 256 + threadIdx.x) * 4;
    if (i < W_ELEMS) {
        float4 f = *(const float4*)(W + i);
        uint2 r;
        r.x = packbf(f.x, f.y);
        r.y = packbf(f.z, f.w);
        *(uint2*)(ws + i) = r;
    }
}

// 2x2 tap: identical expressions to the reference's inner bilinear (coord chain hoisted)
__device__ inline float tap4(const float* m14, int r0, int c0, float fy, float fx) {
    int r1 = min(r0 + 1, 13);
    int c1 = min(c0 + 1, 13);
    float g00 = m14[r0 * 14 + c0];
    float g01 = m14[r0 * 14 + c1];
    float g10 = m14[r1 * 14 + c0];
    float g11 = m14[r1 * 14 + c1];
    return g00 * (1.f - fy) * (1.f - fx) + g01 * (1.f - fy) * fx +
           g10 * fy * (1.f - fx) + g11 * fy * fx;
}

// ===================== GEMM kernel: 64(M) x 80(N), B LDS super-staged, A per-lane regs ==============
// R5 post-mortem: TLP (blocks/CU), not ILP, is the lever — the compiler collapses source-level
// register pipelines (VGPR 52/56 measured). 1280 blocks -> 4 resident/CU (LDS-capped): when one
// block drains its barrier, 3 others keep the SIMDs fed.
// B only: [buf][k-slab][80 rows * 32 bf16], each slab uses the proven XOR-chunk swizzle.
struct GemmSm { unsigned short B[2][4][80 * 32]; };   // 40960 B -> 4 blocks/CU

template <bool USE_WS>
__global__ __launch_bounds__(256, 4) void gemm_kernel(const float* __restrict__ E,
                                                      const float* __restrict__ W,
                                                      const float* __restrict__ bias,
                                                      const unsigned short* __restrict__ wsW,
                                                      float* __restrict__ out) {
    __shared__ __align__(16) GemmSm sg;

    const int bx = blockIdx.x;
    const int t  = threadIdx.x;
    const int wv = t >> 6, ln = t & 63;

    // XCD remap: 1280 = 8 XCDs * 160; 160 = 32 bands * 5 n (bijective). All 5 n-sharers
    // of an A band land on the same XCD, adjacent in dispatch -> A + W L2-resident.
    const int xcd = bx & 7;
    const int j   = bx >> 3;            // 0..159
    const int n0  = (j % 5) * 80;
    const int m0  = (xcd * 32 + j / 5) * 64;
    const int quad = ln >> 4, l16 = ln & 15;

    // A frag source: lane (quad,l16) needs row wv*16+l16, k = it*32 + quad*8..+7
    const float* aptr = E + (size_t)(m0 + wv * 16 + l16) * DIM + quad * 8;

    floatx4 acc[5];
#pragma unroll
    for (int ni = 0; ni < 5; ++ni) acc[ni] = (floatx4){0.f, 0.f, 0.f, 0.f};

    if constexpr (USE_WS) {
        // stage one 4-slab super (80 x 128 bf16 = 20 KB): wave wv stages slab wv entirely.
        auto stageB = [&](int s, int buf) {
            unsigned short* dst = &sg.B[buf][wv][0];
            const int rr = ln >> 2, ch = ln & 3;
#pragma unroll
            for (int c = 0; c < 5; ++c) {
                int row = c * 16 + rr;
                const unsigned short* src = wsW + (size_t)(n0 + row) * DIM +
                                            s * 128 + wv * 32 + 8 * (ch ^ ((row >> 1) & 3));
                gload16(src, dst + c * 512);
            }
        };

        float4 pf[2][2];   // 2-deep A pipeline (16 VGPR)
        auto LDA = [&](int it, int d) {
            pf[d][0] = *(const float4*)(aptr + it * 32);
            pf[d][1] = *(const float4*)(aptr + it * 32 + 4);
        };

        stageB(0, 0);
        LDA(0, 0);
        LDA(1, 1);
        __syncthreads();   // drain prologue (super 0 + A0/A1 regs)

#pragma unroll
        for (int s = 0; s < 6; ++s) {
            if (s < 5) stageB(s + 1, (s + 1) & 1);   // 4 compute-iters of cover
#pragma unroll
            for (int j4 = 0; j4 < 4; ++j4) {
                const int it = s * 4 + j4;
                const int pb = it & 1;
                short8 af = cvt8(pf[pb][0], pf[pb][1]);
                if (it < 22) LDA(it + 2, pb);              // issue early
                __builtin_amdgcn_sched_barrier(0);         // pin: loads stay issued here
                const unsigned short* bb = &sg.B[s & 1][j4][0];
#pragma unroll
                for (int ni = 0; ni < 5; ++ni) {
                    int row = ni * 16 + l16;
                    short8 bfr = *(const short8*)(bb + row * 32 + 8 * (quad ^ ((row >> 1) & 3)));
                    acc[ni] = __builtin_amdgcn_mfma_f32_16x16x32_bf16(af, bfr, acc[ni], 0, 0, 0);
                }
            }
            __syncthreads();   // end of super: readers of buf[s&1] done; drains stage(s+1)
        }
    } else {
        // fallback (no workspace): B per-lane from global fp32, no LDS in GEMM path
#pragma unroll 4
        for (int it = 0; it < 24; ++it) {
            short8 af = cvt8(*(const float4*)(aptr + it * 32), *(const float4*)(aptr + it * 32 + 4));
#pragma unroll
            for (int ni = 0; ni < 5; ++ni) {
                const float* wp = W + (size_t)(n0 + ni * 16 + l16) * DIM + it * 32 + quad * 8;
                short8 bfr = cvt8(*(const float4*)wp, *(const float4*)(wp + 4));
                acc[ni] = __builtin_amdgcn_mfma_f32_16x16x32_bf16(af, bfr, acc[ni], 0, 0, 0);
            }
        }
    }

    // epilogue: C/D layout col=lane&15, row=quad*4+reg (HW-verified)
    const int rowBase = m0 + wv * 16 + quad * 4;
#pragma unroll
    for (int ni = 0; ni < 5; ++ni) {
        int col = n0 + ni * 16 + l16;
        float bv = bias[col];
#pragma unroll
        for (int r = 0; r < 4; ++r) {
            out[(size_t)(rowBase + r) * NCLS + col] = acc[ni][r] + bv;
        }
    }
}

// ===================== mask kernel: 4 (sample,box) pairs per block, 1 per wave =====================
struct MaskSm { float m14[4][208]; float a7[4][56]; float mv[4][56]; };  // 5120 B

__global__ __launch_bounds__(256, 8) void mask_kernel(const float* __restrict__ attn,
                                                      const int* __restrict__ pos,
                                                      float* __restrict__ out) {
    __shared__ __align__(16) MaskSm sm;

    const int bx = blockIdx.x;
    const int t  = threadIdx.x;
    const int wv = t >> 6, ln = t & 63;

    // pairing: waves (2k, 2k+1) hold (b, o=0) and (b, o=1) of the SAME sample ->
    // the 784-B attn row is fetched from HBM once per block instead of twice globally.
    const int p = bx * 4 + wv;   // 0..16383
    const int b = p >> 1;
    const int o = p & 1;
    float* m14 = sm.m14[wv];

    for (int i = ln; i < 196; i += 64) m14[i] = attn[(size_t)b * 196 + i];

    const int* pb = pos + (size_t)b * 12;
    const float topf  = (float)(pb[o * 4 + 0] - pb[8]);
    const float leftf = (float)(pb[o * 4 + 1] - pb[9]);
    const float oH = (float)pb[o * 4 + 2];
    const float oW = (float)pb[o * 4 + 3];
    const float eH = (float)pb[10];
    const float eW = (float)pb[11];
    __syncthreads();

    const int i7 = ln / 7, j7 = ln - i7 * 7;
    if (ln < 49) {
        // hoisted coordinate chains (identical expressions to reference; computed once)
        int   cI[2][2];  float cF[2][2];  float wxs[2];   // [dx][which X]
        int   rI[2][2];  float rF[2][2];  float wys[2];   // [dy][which Y]
#pragma unroll
        for (int dx = 0; dx < 2; ++dx) {
            int ox = 2 * j7 + dx;
            float tx = fmaxf((ox + 0.5f) * oW / 14.0f - 0.5f, 0.0f);
            float x0 = floorf(tx);
            float x1 = fminf(x0 + 1.0f, oW - 1.0f);
            wxs[dx] = tx - x0;
            float X0 = leftf + x0, X1 = leftf + x1;
            float sx0 = fmaxf((X0 + 0.5f) * 14.0f / eW - 0.5f, 0.0f);
            float c0f = floorf(sx0);
            cI[dx][0] = (int)c0f; cF[dx][0] = sx0 - c0f;
            float sx1 = fmaxf((X1 + 0.5f) * 14.0f / eW - 0.5f, 0.0f);
            float c1f = floorf(sx1);
            cI[dx][1] = (int)c1f; cF[dx][1] = sx1 - c1f;
        }
#pragma unroll
        for (int dy = 0; dy < 2; ++dy) {
            int oy = 2 * i7 + dy;
            float ty = fmaxf((oy + 0.5f) * oH / 14.0f - 0.5f, 0.0f);
            float y0 = floorf(ty);
            float y1 = fminf(y0 + 1.0f, oH - 1.0f);
            wys[dy] = ty - y0;
            float Y0 = topf + y0, Y1 = topf + y1;
            float sy0 = fmaxf((Y0 + 0.5f) * 14.0f / eH - 0.5f, 0.0f);
            float r0f = floorf(sy0);
            rI[dy][0] = (int)r0f; rF[dy][0] = sy0 - r0f;
            float sy1 = fmaxf((Y1 + 0.5f) * 14.0f / eH - 0.5f, 0.0f);
            float r1f = floorf(sy1);
            rI[dy][1] = (int)r1f; rF[dy][1] = sy1 - r1f;
        }

        float s = 0.f;
#pragma unroll
        for (int dy = 0; dy < 2; ++dy) {
            float wy = wys[dy];
#pragma unroll
            for (int dx = 0; dx < 2; ++dx) {
                float wx = wxs[dx];
                float v00 = tap4(m14, rI[dy][0], cI[dx][0], rF[dy][0], cF[dx][0]);
                float v01 = tap4(m14, rI[dy][0], cI[dx][1], rF[dy][0], cF[dx][1]);
                float v10 = tap4(m14, rI[dy][1], cI[dx][0], rF[dy][1], cF[dx][0]);
                float v11 = tap4(m14, rI[dy][1], cI[dx][1], rF[dy][1], cF[dx][1]);
                float cm = v00 * (1.f - wy) * (1.f - wx) + v01 * (1.f - wy) * wx +
                           v10 * wy * (1.f - wx) + v11 * wy * wx;
                s += cm;
            }
        }
        sm.a7[wv][ln] = s * 0.25f;
    }
    __syncthreads();

    if (ln < 49) {  // stable top-25 rank (jax.lax.top_k tie-break to lower index)
        float mine = sm.a7[wv][ln];
        int cnt = 0;
#pragma unroll 7
        for (int s2 = 0; s2 < 49; ++s2) {
            float v = sm.a7[wv][s2];
            cnt += (v > mine) || (v == mine && s2 < ln);
        }
        sm.mv[wv][ln] = (cnt < 25) ? 0.0f : 1.0f;
    }
    __syncthreads();

    float* ob = out + LOGITS_SIZE + (size_t)(o * BSAMP + b) * 196;
    for (int i = ln; i < 196; i += 64) {
        int oy = i / 14, ox = i - oy * 14;
        ob[i] = sm.mv[wv][(oy >> 1) * 7 + (ox >> 1)];
    }
}

extern "C" void kernel_launch(void* const* d_in, const int* in_sizes, int n_in,
                              void* d_out, int out_size, void* d_ws, size_t ws_size,
                              hipStream_t stream) {
    const float* attn = (const float*)d_in[0];
    const int*   pos  = (const int*)d_in[1];
    const float* E    = (const float*)d_in[2];
    const float* W    = (const float*)d_in[3];
    const float* bias = (const float*)d_in[4];
    float* out = (float*)d_out;

    if (ws_size >= (size_t)W_ELEMS * 2) {
        unsigned short* ws = (unsigned short*)d_ws;
        cvtW_kernel<<<300, 256, 0, stream>>>(W, ws);
        gemm_kernel<true><<<GEMM_BLOCKS, 256, 0, stream>>>(E, W, bias, ws, out);
    } else {
        gemm_kernel<false><<<GEMM_BLOCKS, 256, 0, stream>>>(E, W, bias, nullptr, out);
    }
    mask_kernel<<<MASK_BLOCKS, 256, 0, stream>>>(attn, pos, out);
}

// Round 7
// 147.288 us; speedup vs baseline: 1.3296x; 1.1256x over previous
//
#include <hip/hip_runtime.h>
#include <hip/hip_bf16.h>
#include <stdint.h>
#include <type_traits>

#define BSAMP 8192
#define NCLS 400
#define DIM 768
#define LOGITS_SIZE (16384LL * 400LL)
#define GEMM_BLOCKS 256     // one 64-row band per block, FULL N=400 -> A read exactly once
#define MASK_BLOCKS 4096    // 4 (sample,box) pairs per block, 1 per wave
#define W_ELEMS (NCLS * DIM)

typedef __attribute__((ext_vector_type(8))) short short8;
typedef __attribute__((ext_vector_type(4))) float floatx4;

// fp32 -> bf16 round-half-up, two at a time: 2 adds + 1 v_perm
__device__ inline unsigned int packbf(float a, float b) {
    unsigned int ua = __float_as_uint(a) + 0x8000u;
    unsigned int ub = __float_as_uint(b) + 0x8000u;
    return __builtin_amdgcn_perm(ub, ua, 0x07060302u);  // [ua.b2,ua.b3,ub.b2,ub.b3]
}

__device__ inline short8 cvt8(float4 lo, float4 hi) {
    union { unsigned int u[4]; short8 s; } r;
    r.u[0] = packbf(lo.x, lo.y);
    r.u[1] = packbf(lo.z, lo.w);
    r.u[2] = packbf(hi.x, hi.y);
    r.u[3] = packbf(hi.z, hi.w);
    return r.s;
}

// async global->LDS DMA, 16 B/lane, dest = wave-uniform base + lane*16.
__device__ inline void gload16(const void* g, void* l) {
    __builtin_amdgcn_global_load_lds((const __attribute__((address_space(1))) void*)g,
                                     (__attribute__((address_space(3))) void*)l, 16, 0, 0);
}

// W fp32 -> bf16 pre-convert (0.6 MB into d_ws); re-run every launch (ws re-poisoned)
__global__ void cvtW_kernel(const float* __restrict__ W, unsigned short* __restrict__ ws) {
    int i = (blockIdx.x * 256 + threadIdx.x) * 4;
    if (i < W_ELEMS) {
        float4 f = *(const float4*)(W + i);
        uint2 r;
        r.x = packbf(f.x, f.y);
        r.y = packbf(f.z, f.w);
        *(uint2*)(ws + i) = r;
    }
}

// 2x2 tap: identical expressions to the reference's inner bilinear (coord chain hoisted)
__device__ inline float tap4(const float* m14, int r0, int c0, float fy, float fx) {
    int r1 = min(r0 + 1, 13);
    int c1 = min(c0 + 1, 13);
    float g00 = m14[r0 * 14 + c0];
    float g01 = m14[r0 * 14 + c1];
    float g10 = m14[r1 * 14 + c0];
    float g11 = m14[r1 * 14 + c1];
    return g00 * (1.f - fy) * (1.f - fx) + g01 * (1.f - fy) * fx +
           g10 * fy * (1.f - fx) + g11 * fy * fx;
}

// ============== GEMM kernel: 64(M) x 400(N=all classes), A read ONCE, B L2-resident ==============
// R6 post-mortem: the invariant across all schedules was 251 MB of A re-reads (5 n-sharers)
// at ~4.7 TB/s through L3 — the real limiter. One block per band kills the re-read entirely:
// A traffic 251 -> 50 MB; W (0.6 MB bf16) is L2-resident; each output row written contiguously
// by one wave. 25 MFMAs per A-frag per k-iter = big latency-cover window per wave.
// B LDS: [buf][400 rows][64 k] bf16, per-64B-slab XOR-chunk swizzle (proven, 0 conflicts).
struct GemmSm { unsigned short B[2][400 * 64]; };   // 102400 B -> 1 block/CU (grid=256, by design)

template <bool USE_WS>
__global__ __launch_bounds__(256, 1) void gemm_kernel(const float* __restrict__ E,
                                                      const float* __restrict__ W,
                                                      const float* __restrict__ bias,
                                                      const unsigned short* __restrict__ wsW,
                                                      float* __restrict__ out) {
    __shared__ __align__(16) GemmSm sg;

    const int bx = blockIdx.x;
    const int t  = threadIdx.x;
    const int wv = t >> 6, ln = t & 63;

    const int m0 = bx * 64;                 // unique band: A element read exactly once per kernel
    const int quad = ln >> 4, l16 = ln & 15;

    // A frag source: lane (quad,l16) needs row wv*16+l16, k = it*32 + quad*8..+7
    const float* aptr = E + (size_t)(m0 + wv * 16 + l16) * DIM + quad * 8;

    floatx4 acc[25];
#pragma unroll
    for (int ni = 0; ni < 25; ++ni) acc[ni] = (floatx4){0.f, 0.f, 0.f, 0.f};

    if constexpr (USE_WS) {
        // stage super s = k-slab [s*64, s*64+64) for all 400 rows: 51.2 KB, 50 gload16-chunks.
        // chunk c covers rows c*8..c*8+7 (128 B/row); lane ln -> row c*8+(ln>>3), 16B-chunk ln&7.
        // within each 64-B half-row (slab), phys 16B-chunk q holds logical q^((row>>1)&3).
        auto stageB = [&](int s, int buf) {
            unsigned short* base = &sg.B[buf][0];
            for (int c = wv; c < 50; c += 4) {
                int row = c * 8 + (ln >> 3);
                const unsigned short* src = wsW + (size_t)row * DIM + s * 64 +
                                            ((ln >> 2) & 1) * 32 +
                                            8 * ((ln & 3) ^ ((row >> 1) & 3));
                gload16(src, base + c * 512);
            }
        };

        float4 pf[2][2];   // 2-deep A lookahead
        auto LDA = [&](int it, int d) {
            pf[d][0] = *(const float4*)(aptr + it * 32);
            pf[d][1] = *(const float4*)(aptr + it * 32 + 4);
        };

        stageB(0, 0);
        LDA(0, 0);
        LDA(1, 1);
        __syncthreads();   // drain prologue (super 0 + A0/A1 regs)

#pragma unroll
        for (int s = 0; s < 12; ++s) {
            if (s < 11) stageB(s + 1, (s + 1) & 1);   // 2 k-iters of cover
#pragma unroll
            for (int kk = 0; kk < 2; ++kk) {
                const int it = s * 2 + kk;
                const int pb = it & 1;
                short8 af = cvt8(pf[pb][0], pf[pb][1]);
                if (it < 22) LDA(it + 2, pb);          // issue early
                __builtin_amdgcn_sched_barrier(0);     // pin: loads stay issued here
                const unsigned short* bb = &sg.B[s & 1][0];
#pragma unroll
                for (int ni = 0; ni < 25; ++ni) {
                    int row = ni * 16 + l16;
                    short8 bfr = *(const short8*)(bb + row * 64 + kk * 32 +
                                                  8 * (quad ^ ((row >> 1) & 3)));
                    acc[ni] = __builtin_amdgcn_mfma_f32_16x16x32_bf16(af, bfr, acc[ni], 0, 0, 0);
                }
            }
            __syncthreads();   // end of super: readers of buf[s&1] done; drains stage(s+1)
        }
    } else {
        // fallback (no workspace): B per-lane from global fp32
        for (int it = 0; it < 24; ++it) {
            short8 af = cvt8(*(const float4*)(aptr + it * 32), *(const float4*)(aptr + it * 32 + 4));
#pragma unroll
            for (int ni = 0; ni < 25; ++ni) {
                const float* wp = W + (size_t)(ni * 16 + l16) * DIM + it * 32 + quad * 8;
                short8 bfr = cvt8(*(const float4*)wp, *(const float4*)(wp + 4));
                acc[ni] = __builtin_amdgcn_mfma_f32_16x16x32_bf16(af, bfr, acc[ni], 0, 0, 0);
            }
        }
    }

    // epilogue: C/D layout col=lane&15, row=quad*4+reg (HW-verified). One wave writes a row's
    // full 1600 B (25 x 64-B segments) -> clean L2 write-combining, no cross-CU assembly.
    const int rowBase = m0 + wv * 16 + quad * 4;
#pragma unroll
    for (int ni = 0; ni < 25; ++ni) {
        int col = ni * 16 + l16;
        float bv = bias[col];
#pragma unroll
        for (int r = 0; r < 4; ++r) {
            out[(size_t)(rowBase + r) * NCLS + col] = acc[ni][r] + bv;
        }
    }
}

// ===================== mask kernel: 4 (sample,box) pairs per block, 1 per wave =====================
struct MaskSm { float m14[4][208]; float a7[4][56]; float mv[4][56]; };  // 5120 B

__global__ __launch_bounds__(256, 8) void mask_kernel(const float* __restrict__ attn,
                                                      const int* __restrict__ pos,
                                                      float* __restrict__ out) {
    __shared__ __align__(16) MaskSm sm;

    const int bx = blockIdx.x;
    const int t  = threadIdx.x;
    const int wv = t >> 6, ln = t & 63;

    // pairing: waves (2k, 2k+1) hold (b, o=0) and (b, o=1) of the SAME sample ->
    // the 784-B attn row is fetched from HBM once per block instead of twice globally.
    const int p = bx * 4 + wv;   // 0..16383
    const int b = p >> 1;
    const int o = p & 1;
    float* m14 = sm.m14[wv];

    for (int i = ln; i < 196; i += 64) m14[i] = attn[(size_t)b * 196 + i];

    const int* pb = pos + (size_t)b * 12;
    const float topf  = (float)(pb[o * 4 + 0] - pb[8]);
    const float leftf = (float)(pb[o * 4 + 1] - pb[9]);
    const float oH = (float)pb[o * 4 + 2];
    const float oW = (float)pb[o * 4 + 3];
    const float eH = (float)pb[10];
    const float eW = (float)pb[11];
    __syncthreads();

    const int i7 = ln / 7, j7 = ln - i7 * 7;
    if (ln < 49) {
        // hoisted coordinate chains (identical expressions to reference; computed once)
        int   cI[2][2];  float cF[2][2];  float wxs[2];   // [dx][which X]
        int   rI[2][2];  float rF[2][2];  float wys[2];   // [dy][which Y]
#pragma unroll
        for (int dx = 0; dx < 2; ++dx) {
            int ox = 2 * j7 + dx;
            float tx = fmaxf((ox + 0.5f) * oW / 14.0f - 0.5f, 0.0f);
            float x0 = floorf(tx);
            float x1 = fminf(x0 + 1.0f, oW - 1.0f);
            wxs[dx] = tx - x0;
            float X0 = leftf + x0, X1 = leftf + x1;
            float sx0 = fmaxf((X0 + 0.5f) * 14.0f / eW - 0.5f, 0.0f);
            float c0f = floorf(sx0);
            cI[dx][0] = (int)c0f; cF[dx][0] = sx0 - c0f;
            float sx1 = fmaxf((X1 + 0.5f) * 14.0f / eW - 0.5f, 0.0f);
            float c1f = floorf(sx1);
            cI[dx][1] = (int)c1f; cF[dx][1] = sx1 - c1f;
        }
#pragma unroll
        for (int dy = 0; dy < 2; ++dy) {
            int oy = 2 * i7 + dy;
            float ty = fmaxf((oy + 0.5f) * oH / 14.0f - 0.5f, 0.0f);
            float y0 = floorf(ty);
            float y1 = fminf(y0 + 1.0f, oH - 1.0f);
            wys[dy] = ty - y0;
            float Y0 = topf + y0, Y1 = topf + y1;
            float sy0 = fmaxf((Y0 + 0.5f) * 14.0f / eH - 0.5f, 0.0f);
            float r0f = floorf(sy0);
            rI[dy][0] = (int)r0f; rF[dy][0] = sy0 - r0f;
            float sy1 = fmaxf((Y1 + 0.5f) * 14.0f / eH - 0.5f, 0.0f);
            float r1f = floorf(sy1);
            rI[dy][1] = (int)r1f; rF[dy][1] = sy1 - r1f;
        }

        float s = 0.f;
#pragma unroll
        for (int dy = 0; dy < 2; ++dy) {
            float wy = wys[dy];
#pragma unroll
            for (int dx = 0; dx < 2; ++dx) {
                float wx = wxs[dx];
                float v00 = tap4(m14, rI[dy][0], cI[dx][0], rF[dy][0], cF[dx][0]);
                float v01 = tap4(m14, rI[dy][0], cI[dx][1], rF[dy][0], cF[dx][1]);
                float v10 = tap4(m14, rI[dy][1], cI[dx][0], rF[dy][1], cF[dx][0]);
                float v11 = tap4(m14, rI[dy][1], cI[dx][1], rF[dy][1], cF[dx][1]);
                float cm = v00 * (1.f - wy) * (1.f - wx) + v01 * (1.f - wy) * wx +
                           v10 * wy * (1.f - wx) + v11 * wy * wx;
                s += cm;
            }
        }
        sm.a7[wv][ln] = s * 0.25f;
    }
    __syncthreads();

    if (ln < 49) {  // stable top-25 rank (jax.lax.top_k tie-break to lower index)
        float mine = sm.a7[wv][ln];
        int cnt = 0;
#pragma unroll 7
        for (int s2 = 0; s2 < 49; ++s2) {
            float v = sm.a7[wv][s2];
            cnt += (v > mine) || (v == mine && s2 < ln);
        }
        sm.mv[wv][ln] = (cnt < 25) ? 0.0f : 1.0f;
    }
    __syncthreads();

    float* ob = out + LOGITS_SIZE + (size_t)(o * BSAMP + b) * 196;
    for (int i = ln; i < 196; i += 64) {
        int oy = i / 14, ox = i - oy * 14;
        ob[i] = sm.mv[wv][(oy >> 1) * 7 + (ox >> 1)];
    }
}

extern "C" void kernel_launch(void* const* d_in, const int* in_sizes, int n_in,
                              void* d_out, int out_size, void* d_ws, size_t ws_size,
                              hipStream_t stream) {
    const float* attn = (const float*)d_in[0];
    const int*   pos  = (const int*)d_in[1];
    const float* E    = (const float*)d_in[2];
    const float* W    = (const float*)d_in[3];
    const float* bias = (const float*)d_in[4];
    float* out = (float*)d_out;

    if (ws_size >= (size_t)W_ELEMS * 2) {
        unsigned short* ws = (unsigned short*)d_ws;
        cvtW_kernel<<<300, 256, 0, stream>>>(W, ws);
        gemm_kernel<true><<<GEMM_BLOCKS, 256, 0, stream>>>(E, W, bias, ws, out);
    } else {
        gemm_kernel<false><<<GEMM_BLOCKS, 256, 0, stream>>>(E, W, bias, nullptr, out);
    }
    mask_kernel<<<MASK_BLOCKS, 256, 0, stream>>>(attn, pos, out);
}